// Round 10
// baseline (435.441 us; speedup 1.0000x reference)
//
#include <hip/hip_runtime.h>

#define H_DIM 1024
#define NHEADS 16
#define HD 64
#define SEQ 1024
#define BATCH 8
#define ROWS (BATCH*SEQ)   // 8192
#define MLPD 4096

typedef __bf16 bf16x8 __attribute__((ext_vector_type(8)));
typedef float f32x4 __attribute__((ext_vector_type(4)));

__device__ __forceinline__ unsigned short f2bf(float f) {
    unsigned u = __float_as_uint(f);
    unsigned r = u + 0x7FFFu + ((u >> 16) & 1u);   // RNE
    return (unsigned short)(r >> 16);
}

// ---------------- weight transpose fp32(K,N) -> bf16(N,K) ----------------
__global__ void transpose_w(const float* __restrict__ in, unsigned short* __restrict__ out,
                            int K, int N)
{
    __shared__ float tile[32][33];
    const int n0 = blockIdx.x * 32, k0 = blockIdx.y * 32;
    const int tx = threadIdx.x, ty = threadIdx.y;      // (32,8)
    #pragma unroll
    for (int i = ty; i < 32; i += 8)
        tile[i][tx] = in[(size_t)(k0 + i) * N + n0 + tx];
    __syncthreads();
    #pragma unroll
    for (int i = ty; i < 32; i += 8)
        out[(size_t)(n0 + i) * K + k0 + tx] = f2bf(tile[tx][i]);
}

// ---- per-head bf16 transpose with kv-permuted columns (R6-validated) ----
__global__ void transpose_v(const unsigned short* __restrict__ in,
                            unsigned short* __restrict__ out)
{
    __shared__ unsigned short tile[32][33];
    const size_t base = (size_t)blockIdx.z * (SEQ * HD);
    const int d0 = blockIdx.x * 32, s0 = blockIdx.y * 32;
    const int tx = threadIdx.x, ty = threadIdx.y;      // (32,8)
    #pragma unroll
    for (int i = ty; i < 32; i += 8)
        tile[i][tx] = in[base + (size_t)(s0 + i) * HD + d0 + tx];
    __syncthreads();
    const int fx = ((tx & 12) << 1) | ((tx & 16) >> 2) | (tx & 3);   // kv -> kv'
    #pragma unroll
    for (int i = ty; i < 32; i += 8)
        out[base + (size_t)(d0 + i) * SEQ + s0 + fx] = tile[tx][i];
}

// ---------------- layernorm fp32 -> bf16, one block per row ----------------
__global__ __launch_bounds__(256) void ln_kernel(const float* __restrict__ x,
    const float* __restrict__ g, const float* __restrict__ b,
    unsigned short* __restrict__ out)
{
    __shared__ float red[4];
    const int row = blockIdx.x;
    const int tid = threadIdx.x;
    const float4 v = *(const float4*)(x + (size_t)row * H_DIM + tid * 4);
    float s = v.x + v.y + v.z + v.w;
    #pragma unroll
    for (int off = 32; off >= 1; off >>= 1) s += __shfl_xor(s, off);
    if ((tid & 63) == 0) red[tid >> 6] = s;
    __syncthreads();
    const float mu = (red[0] + red[1] + red[2] + red[3]) * (1.0f / H_DIM);
    __syncthreads();
    const float dx = v.x - mu, dy = v.y - mu, dz = v.z - mu, dw = v.w - mu;
    float q = dx * dx + dy * dy + dz * dz + dw * dw;
    #pragma unroll
    for (int off = 32; off >= 1; off >>= 1) q += __shfl_xor(q, off);
    if ((tid & 63) == 0) red[tid >> 6] = q;
    __syncthreads();
    const float var = (red[0] + red[1] + red[2] + red[3]) * (1.0f / H_DIM);
    const float rstd = rsqrtf(var + 1e-6f);
    const float4 gv = *(const float4*)(g + tid * 4);
    const float4 bv = *(const float4*)(b + tid * 4);
    ushort4 o;
    o.x = f2bf(dx * rstd * gv.x + bv.x);
    o.y = f2bf(dy * rstd * gv.y + bv.y);
    o.z = f2bf(dz * rstd * gv.z + bv.z);
    o.w = f2bf(dw * rstd * gv.w + bv.w);
    *(ushort4*)(out + (size_t)row * H_DIM + tid * 4) = o;
}

// ---------------- bf16 GEMM: C = A(MxK) * Bt(NxK)^T -----------------------
// BM=256, BN=128, BK=64. 512 threads = 8 waves (4M x 2N), 64x64 per wave.
// Single-buffer 2-barrier loop (R7/R9 A/B showed buffering-insensitivity ->
// limit is staged bytes/FLOP; 256x128 cuts KB/MFLOP 15.6 -> 11.4 and doubles
// per-CU MFMA work per drain). LDS 48 KB -> up to 3 blocks/CU.
// T2 swizzle (conflict-free, R3-validated), T1 XCD swizzle, T5 setprio.
// No min-waves clause (R8 lesson: it forces acc spills).
// MODE 0: fused QKV -> bf16 [B,NH,S,HD] x3    MODE 2: f32 out = resid + C
// MODE 3: bf16 out = gelu_tanh(C) (exp2-based, |err| ~1e-3 abs)
template<int MODE>
__global__ __launch_bounds__(512) void gemm_dp(
    const unsigned short* __restrict__ A, const unsigned short* __restrict__ Bt,
    const float* __restrict__ bias0, const float* __restrict__ bias1,
    const float* __restrict__ bias2, const float* resid,
    float* outF, unsigned short* __restrict__ outH,
    int N, int K, int gn)
{
    __shared__ __align__(16) unsigned short As[256 * 64];   // 32 KB
    __shared__ __align__(16) unsigned short Bs[128 * 64];   // 16 KB

    const int tid = threadIdx.x, lane = tid & 63;
    const int w = tid >> 6;             // 0..7
    const int wm = w >> 1, wn = w & 1;  // 4M x 2N wave grid, 64x64 per wave

    // T1: bijective XCD swizzle (nwg % 8 == 0 for all our launches)
    const int nwg = gridDim.x;
    const int swzb = (blockIdx.x & 7) * (nwg >> 3) + (blockIdx.x >> 3);
    const int bm = swzb / gn, bn = swzb % gn;

    const int srow = tid >> 3;                       // 0..63
    const int sc = (tid & 7) ^ (srow & 7);           // pre-swizzled global 16B chunk
    const unsigned short* Abase = A  + (size_t)(bm * 256) * K;
    const unsigned short* Bbase = Bt + (size_t)(bn * 128) * K;

    // stage one K-tile: A 4 rounds (64 rows each) + B 2 rounds
    auto stage = [&](int kt) {
        const size_t kofs = (size_t)kt * 64 + sc * 8;
        #pragma unroll
        for (int q = 0; q < 4; ++q)
            __builtin_amdgcn_global_load_lds(
                (__attribute__((address_space(1))) void*)(Abase + (size_t)(q * 64 + srow) * K + kofs),
                (__attribute__((address_space(3))) void*)(&As[q * 4096 + tid * 8]), 16, 0, 0);
        #pragma unroll
        for (int q = 0; q < 2; ++q)
            __builtin_amdgcn_global_load_lds(
                (__attribute__((address_space(1))) void*)(Bbase + (size_t)(q * 64 + srow) * K + kofs),
                (__attribute__((address_space(3))) void*)(&Bs[q * 4096 + tid * 8]), 16, 0, 0);
    };

    const int lr = lane & 15, hk = lane >> 4;
    const int px0 = (hk ^ (lr & 7)) * 8;             // kstep0 physical chunk (elems)
    const int px1 = px0 ^ 32;                        // kstep1
    const int arow = (wm * 64 + lr) * 64;
    const int brow = (wn * 64 + lr) * 64;

    f32x4 acc[4][4] = {};
    const int nkt = K >> 6;

    for (int t = 0; t < nkt; ++t) {
        stage(t);
        __syncthreads();                 // drains vmcnt(0): stage(t) landed

        const unsigned short* Ab = &As[arow];
        const unsigned short* Bb = &Bs[brow];

        bf16x8 a0[4], b0[4], a1[4], b1[4];
        #pragma unroll
        for (int i = 0; i < 4; ++i) { b0[i] = *(const bf16x8*)(Bb + i * 1024 + px0);
                                      a0[i] = *(const bf16x8*)(Ab + i * 1024 + px0); }
        #pragma unroll
        for (int i = 0; i < 4; ++i) { b1[i] = *(const bf16x8*)(Bb + i * 1024 + px1);
                                      a1[i] = *(const bf16x8*)(Ab + i * 1024 + px1); }
        __builtin_amdgcn_s_setprio(1);
        #pragma unroll
        for (int mi = 0; mi < 4; ++mi)
            #pragma unroll
            for (int ni = 0; ni < 4; ++ni)
                acc[mi][ni] = __builtin_amdgcn_mfma_f32_16x16x32_bf16(a0[mi], b0[ni], acc[mi][ni], 0, 0, 0);
        __builtin_amdgcn_s_setprio(0);
        __builtin_amdgcn_s_setprio(1);
        #pragma unroll
        for (int mi = 0; mi < 4; ++mi)
            #pragma unroll
            for (int ni = 0; ni < 4; ++ni)
                acc[mi][ni] = __builtin_amdgcn_mfma_f32_16x16x32_bf16(a1[mi], b1[ni], acc[mi][ni], 0, 0, 0);
        __builtin_amdgcn_s_setprio(0);
        __syncthreads();                 // all reads done before next overwrite
    }

    #pragma unroll
    for (int mi = 0; mi < 4; ++mi) {
        #pragma unroll
        for (int ni = 0; ni < 4; ++ni) {
            const int gcol = bn * 128 + wn * 64 + ni * 16 + lr;
            #pragma unroll
            for (int r = 0; r < 4; ++r) {
                const int grow = bm * 256 + wm * 64 + mi * 16 + hk * 4 + r;
                if (MODE == 0) {
                    const int which = gcol >> 10;              // 0=Q 1=K 2=V
                    const int col = gcol & 1023;
                    const float* bp = (which == 0) ? bias0 : (which == 1) ? bias1 : bias2;
                    const float v = acc[mi][ni][r] + bp[col];
                    const int b_ = grow >> 10, s_ = grow & 1023, h_ = col >> 6, d_ = col & 63;
                    outH[(size_t)which * (ROWS * 1024) +
                         (size_t)(b_ * NHEADS + h_) * 65536 + s_ * 64 + d_] = f2bf(v);
                } else if (MODE == 2) {
                    const float v = acc[mi][ni][r] + bias0[gcol];
                    const size_t idx = (size_t)grow * N + gcol;
                    outF[idx] = resid[idx] + v;
                } else {
                    const float v = acc[mi][ni][r] + bias0[gcol];
                    // gelu_tanh: x * sigmoid(1.5957691*(x + 0.044715 x^3)), via exp2
                    const float t3 = fmaf(0.044715f * v * v, v, v);
                    const float e  = __builtin_amdgcn_exp2f(-2.3022086f * t3);
                    const float ge = v * __builtin_amdgcn_rcpf(1.0f + e);
                    outH[(size_t)grow * N + gcol] = f2bf(ge);
                }
            }
        }
    }
}

// ---------------- flash attention (R6-validated) --------------------------
__global__ __launch_bounds__(256) void attn_kernel(const unsigned short* __restrict__ q,
    const unsigned short* __restrict__ k, const unsigned short* __restrict__ vT,
    unsigned short* __restrict__ out)
{
    __shared__ __align__(16) unsigned short Ks[2][4096];   // [64 kv][64 d], swizzled
    __shared__ __align__(16) unsigned short Vs[2][4096];   // [64 d][64 kv'], swizzled
    const int tid = threadIdx.x, lane = tid & 63, w = tid >> 6;
    const int bh = blockIdx.y;
    const int q0 = blockIdx.x * 64;
    const size_t headBase = (size_t)bh * (SEQ * HD);   // 65536

    const int qrow = q0 + w * 16 + (lane & 15);
    const unsigned short* qp = q + headBase + (size_t)qrow * HD + (lane >> 4) * 8;
    const bf16x8 qf0 = *(const bf16x8*)(qp);
    const bf16x8 qf1 = *(const bf16x8*)(qp + 32);

    float lacc = 0.f;
    f32x4 oacc[4] = {};    // oacc[nd][r] = O^T[d=nd*16+4h+r][q=lane&15]

    const int srow = tid >> 3;                          // 0..31
    const int swz  = ((tid & 7) ^ (srow & 7)) * 8;      // pre-swizzled global chunk
    const int pc   = (lane >> 4) ^ (lane & 7);          // physical chunk for swizzled reads

    auto stage = [&](int buf, int kt) {
        #pragma unroll
        for (int s = 0; s < 2; ++s) {
            const unsigned short* gk = k  + headBase + (size_t)(kt + s * 32 + srow) * HD + swz;
            const unsigned short* gv = vT + headBase + (size_t)(s * 32 + srow) * SEQ + kt + swz;
            __builtin_amdgcn_global_load_lds((__attribute__((address_space(1))) void*)gk,
                (__attribute__((address_space(3))) void*)(&Ks[buf][s * 2048 + w * 512]), 16, 0, 0);
            __builtin_amdgcn_global_load_lds((__attribute__((address_space(1))) void*)gv,
                (__attribute__((address_space(3))) void*)(&Vs[buf][s * 2048 + w * 512]), 16, 0, 0);
        }
    };

    stage(0, 0);
    __syncthreads();

    const float C1 = 0.125f * 1.44269504f;      // fold HD^-0.5 into exp2
    const float C2 = -4.0f * 1.44269504f;       // fixed max M = 4

    for (int t = 0; t < 16; ++t) {
        const int cur = t & 1;
        if (t < 15) stage(cur ^ 1, (t + 1) * 64);

        const unsigned short* KB = &Ks[cur][0];
        const unsigned short* VB = &Vs[cur][0];

        // S^T = K·Q^T: s4[ni][r] = S[q=lane&15][kv = ni*16 + 4h + r]
        f32x4 s4[4] = {};
        #pragma unroll
        for (int ni = 0; ni < 4; ++ni) {
            const unsigned short* pk = KB + (ni * 16 + (lane & 15)) * 64;
            s4[ni] = __builtin_amdgcn_mfma_f32_16x16x32_bf16(*(const bf16x8*)(pk + pc * 8),       qf0, s4[ni], 0, 0, 0);
            s4[ni] = __builtin_amdgcn_mfma_f32_16x16x32_bf16(*(const bf16x8*)(pk + (pc ^ 4) * 8), qf1, s4[ni], 0, 0, 0);
        }

        // fixed-max softmax + in-lane bf16 pack
        unsigned U[4][2];
        float ls = 0.f;
        #pragma unroll
        for (int ni = 0; ni < 4; ++ni) {
            const float p0 = __builtin_amdgcn_exp2f(fmaf(s4[ni][0], C1, C2));
            const float p1 = __builtin_amdgcn_exp2f(fmaf(s4[ni][1], C1, C2));
            const float p2 = __builtin_amdgcn_exp2f(fmaf(s4[ni][2], C1, C2));
            const float p3 = __builtin_amdgcn_exp2f(fmaf(s4[ni][3], C1, C2));
            ls += (p0 + p1) + (p2 + p3);
            asm("v_cvt_pk_bf16_f32 %0, %1, %2" : "=v"(U[ni][0]) : "v"(p0), "v"(p1));
            asm("v_cvt_pk_bf16_f32 %0, %1, %2" : "=v"(U[ni][1]) : "v"(p2), "v"(p3));
        }
        lacc += ls;

        union { unsigned u[4]; bf16x8 v; } W0, W1;
        W0.u[0] = U[0][0]; W0.u[1] = U[0][1]; W0.u[2] = U[1][0]; W0.u[3] = U[1][1];
        W1.u[0] = U[2][0]; W1.u[1] = U[2][1]; W1.u[2] = U[3][0]; W1.u[3] = U[3][1];

        // O^T += V^T · P
        #pragma unroll
        for (int nd = 0; nd < 4; ++nd) {
            const unsigned short* pv = VB + (nd * 16 + (lane & 15)) * 64;
            oacc[nd] = __builtin_amdgcn_mfma_f32_16x16x32_bf16(*(const bf16x8*)(pv + pc * 8),       W0.v, oacc[nd], 0, 0, 0);
            oacc[nd] = __builtin_amdgcn_mfma_f32_16x16x32_bf16(*(const bf16x8*)(pv + (pc ^ 4) * 8), W1.v, oacc[nd], 0, 0, 0);
        }

        __syncthreads();
    }

    float l = lacc;
    l += __shfl_xor(l, 16);
    l += __shfl_xor(l, 32);
    const float inv = 1.0f / l;

    const int b_ = bh >> 4, h_ = bh & 15;
    const int s_ = q0 + w * 16 + (lane & 15);
    const int hh = (lane >> 4) * 4;
    #pragma unroll
    for (int nd = 0; nd < 4; ++nd) {
        ushort4 o;
        o.x = f2bf(oacc[nd][0] * inv);
        o.y = f2bf(oacc[nd][1] * inv);
        o.z = f2bf(oacc[nd][2] * inv);
        o.w = f2bf(oacc[nd][3] * inv);
        *(ushort4*)(out + (size_t)(b_ * SEQ + s_) * H_DIM + h_ * 64 + nd * 16 + hh) = o;
    }
}

extern "C" void kernel_launch(void* const* d_in, const int* in_sizes, int n_in,
                              void* d_out, int out_size, void* d_ws, size_t ws_size,
                              hipStream_t stream)
{
    const float* x    = (const float*)d_in[0];
    const float* ln1g = (const float*)d_in[1];
    const float* ln1b = (const float*)d_in[2];
    const float* Wq   = (const float*)d_in[3];
    const float* bq   = (const float*)d_in[4];
    const float* Wk   = (const float*)d_in[5];
    const float* bk   = (const float*)d_in[6];
    const float* Wv   = (const float*)d_in[7];
    const float* bv   = (const float*)d_in[8];
    const float* Wo   = (const float*)d_in[9];
    const float* bo   = (const float*)d_in[10];
    const float* ln2g = (const float*)d_in[11];
    const float* ln2b = (const float*)d_in[12];
    const float* W1   = (const float*)d_in[13];
    const float* b1   = (const float*)d_in[14];
    const float* W2   = (const float*)d_in[15];
    const float* b2   = (const float*)d_in[16];
    float* out = (float*)d_out;

    char* ws = (char*)d_ws;
    const size_t MB = 1024 * 1024;
    unsigned short* h1  = (unsigned short*)(ws);
    unsigned short* qb  = (unsigned short*)(ws + 16 * MB);
    unsigned short* kb  = (unsigned short*)(ws + 32 * MB);
    unsigned short* vb  = (unsigned short*)(ws + 48 * MB);
    unsigned short* vTb = (unsigned short*)(ws + 64 * MB);
    unsigned short* mlp = (unsigned short*)(ws + 16 * MB);
    unsigned short* ao  = h1;
    unsigned short* WqT = (unsigned short*)(ws + 80 * MB);   // contiguous QKV weights
    unsigned short* WkT = (unsigned short*)(ws + 82 * MB);
    unsigned short* WvT = (unsigned short*)(ws + 84 * MB);
    unsigned short* WoT = (unsigned short*)(ws + 86 * MB);
    unsigned short* W1T = (unsigned short*)(ws + 88 * MB);   // 8MB
    unsigned short* W2T = (unsigned short*)(ws + 96 * MB);   // 8MB

    const dim3 tb(32, 8);
    transpose_w<<<dim3(32, 32),  tb, 0, stream>>>(Wq, WqT, 1024, 1024);
    transpose_w<<<dim3(32, 32),  tb, 0, stream>>>(Wk, WkT, 1024, 1024);
    transpose_w<<<dim3(32, 32),  tb, 0, stream>>>(Wv, WvT, 1024, 1024);
    transpose_w<<<dim3(32, 32),  tb, 0, stream>>>(Wo, WoT, 1024, 1024);
    transpose_w<<<dim3(128, 32), tb, 0, stream>>>(W1, W1T, 1024, 4096);
    transpose_w<<<dim3(32, 128), tb, 0, stream>>>(W2, W2T, 4096, 1024);

    ln_kernel<<<ROWS, 256, 0, stream>>>(x, ln1g, ln1b, h1);

    // fused QKV: N = 3072, tile 256x128 -> grid 32x24 = 768 blocks
    gemm_dp<0><<<768, 512, 0, stream>>>(h1, WqT, bq, bk, bv, nullptr, nullptr, qb, 3072, 1024, 24);

    transpose_v<<<dim3(2, 32, 128), tb, 0, stream>>>(vb, vTb);

    attn_kernel<<<dim3(16, 128), 256, 0, stream>>>(qb, kb, vTb, ao);

    // O-proj + residual: 32x8 = 256 blocks
    gemm_dp<2><<<256, 512, 0, stream>>>(ao, WoT, bo, bo, bo, x, out, nullptr, 1024, 1024, 8);

    ln_kernel<<<ROWS, 256, 0, stream>>>(out, ln2g, ln2b, h1);

    // MLP1 + gelu: 32x32 = 1024 blocks
    gemm_dp<3><<<1024, 512, 0, stream>>>(h1, W1T, b1, b1, b1, nullptr, nullptr, mlp, 4096, 1024, 32);
    // MLP2 + residual: 32x8 = 256 blocks
    gemm_dp<2><<<256, 512, 0, stream>>>(mlp, W2T, b2, b2, b2, out, out, nullptr, 1024, 4096, 8);
}

// Round 11
// 395.817 us; speedup vs baseline: 1.1001x; 1.1001x over previous
//
#include <hip/hip_runtime.h>

#define H_DIM 1024
#define NHEADS 16
#define HD 64
#define SEQ 1024
#define BATCH 8
#define ROWS (BATCH*SEQ)   // 8192
#define MLPD 4096

typedef __bf16 bf16x8 __attribute__((ext_vector_type(8)));
typedef float f32x4 __attribute__((ext_vector_type(4)));

__device__ __forceinline__ unsigned short f2bf(float f) {
    unsigned u = __float_as_uint(f);
    unsigned r = u + 0x7FFFu + ((u >> 16) & 1u);   // RNE
    return (unsigned short)(r >> 16);
}

// ---------------- weight transpose fp32(K,N) -> bf16(N,K) ----------------
__global__ void transpose_w(const float* __restrict__ in, unsigned short* __restrict__ out,
                            int K, int N)
{
    __shared__ float tile[32][33];
    const int n0 = blockIdx.x * 32, k0 = blockIdx.y * 32;
    const int tx = threadIdx.x, ty = threadIdx.y;      // (32,8)
    #pragma unroll
    for (int i = ty; i < 32; i += 8)
        tile[i][tx] = in[(size_t)(k0 + i) * N + n0 + tx];
    __syncthreads();
    #pragma unroll
    for (int i = ty; i < 32; i += 8)
        out[(size_t)(n0 + i) * K + k0 + tx] = f2bf(tile[tx][i]);
}

// ---- per-head bf16 transpose with kv-permuted columns (R6-validated) ----
__global__ void transpose_v(const unsigned short* __restrict__ in,
                            unsigned short* __restrict__ out)
{
    __shared__ unsigned short tile[32][33];
    const size_t base = (size_t)blockIdx.z * (SEQ * HD);
    const int d0 = blockIdx.x * 32, s0 = blockIdx.y * 32;
    const int tx = threadIdx.x, ty = threadIdx.y;      // (32,8)
    #pragma unroll
    for (int i = ty; i < 32; i += 8)
        tile[i][tx] = in[base + (size_t)(s0 + i) * HD + d0 + tx];
    __syncthreads();
    const int fx = ((tx & 12) << 1) | ((tx & 16) >> 2) | (tx & 3);   // kv -> kv'
    #pragma unroll
    for (int i = ty; i < 32; i += 8)
        out[base + (size_t)(d0 + i) * SEQ + s0 + fx] = tile[tx][i];
}

// ---------------- layernorm fp32 -> bf16, one block per row ----------------
__global__ __launch_bounds__(256) void ln_kernel(const float* __restrict__ x,
    const float* __restrict__ g, const float* __restrict__ b,
    unsigned short* __restrict__ out)
{
    __shared__ float red[4];
    const int row = blockIdx.x;
    const int tid = threadIdx.x;
    const float4 v = *(const float4*)(x + (size_t)row * H_DIM + tid * 4);
    float s = v.x + v.y + v.z + v.w;
    #pragma unroll
    for (int off = 32; off >= 1; off >>= 1) s += __shfl_xor(s, off);
    if ((tid & 63) == 0) red[tid >> 6] = s;
    __syncthreads();
    const float mu = (red[0] + red[1] + red[2] + red[3]) * (1.0f / H_DIM);
    __syncthreads();
    const float dx = v.x - mu, dy = v.y - mu, dz = v.z - mu, dw = v.w - mu;
    float q = dx * dx + dy * dy + dz * dz + dw * dw;
    #pragma unroll
    for (int off = 32; off >= 1; off >>= 1) q += __shfl_xor(q, off);
    if ((tid & 63) == 0) red[tid >> 6] = q;
    __syncthreads();
    const float var = (red[0] + red[1] + red[2] + red[3]) * (1.0f / H_DIM);
    const float rstd = rsqrtf(var + 1e-6f);
    const float4 gv = *(const float4*)(g + tid * 4);
    const float4 bv = *(const float4*)(b + tid * 4);
    ushort4 o;
    o.x = f2bf(dx * rstd * gv.x + bv.x);
    o.y = f2bf(dy * rstd * gv.y + bv.y);
    o.z = f2bf(dz * rstd * gv.z + bv.z);
    o.w = f2bf(dw * rstd * gv.w + bv.w);
    *(ushort4*)(out + (size_t)row * H_DIM + tid * 4) = o;
}

// ---------------- bf16 GEMM (R9-proven): 128x128, 4 waves, single-buffer ----
// MODE 0: fused QKV -> bf16 [B,NH,S,HD] x3    MODE 2: f32 out = resid + C
template<int MODE>
__global__ __launch_bounds__(256) void gemm_dp(
    const unsigned short* __restrict__ A, const unsigned short* __restrict__ Bt,
    const float* __restrict__ bias0, const float* __restrict__ bias1,
    const float* __restrict__ bias2, const float* resid,
    float* outF, unsigned short* __restrict__ outH,
    int N, int K, int gn)
{
    __shared__ __align__(16) unsigned short As[128 * 64];   // 16 KB
    __shared__ __align__(16) unsigned short Bs[128 * 64];   // 16 KB

    const int tid = threadIdx.x, lane = tid & 63;
    const int w = tid >> 6;
    const int wm = w >> 1, wn = w & 1;  // 2x2 wave grid, 64x64 per wave

    const int nwg = gridDim.x;
    const int swzb = (blockIdx.x & 7) * (nwg >> 3) + (blockIdx.x >> 3);
    const int bm = swzb / gn, bn = swzb % gn;

    const int srow = tid >> 3;                       // 0..31
    const int sc = (tid & 7) ^ (srow & 7);           // pre-swizzled global 16B chunk
    const unsigned short* Abase = A  + (size_t)(bm * 128) * K;
    const unsigned short* Bbase = Bt + (size_t)(bn * 128) * K;

    auto stage = [&](int kt) {
        const size_t kofs = (size_t)kt * 64 + sc * 8;
        #pragma unroll
        for (int q = 0; q < 4; ++q)
            __builtin_amdgcn_global_load_lds(
                (__attribute__((address_space(1))) void*)(Abase + (size_t)(q * 32 + srow) * K + kofs),
                (__attribute__((address_space(3))) void*)(&As[q * 2048 + tid * 8]), 16, 0, 0);
        #pragma unroll
        for (int q = 0; q < 4; ++q)
            __builtin_amdgcn_global_load_lds(
                (__attribute__((address_space(1))) void*)(Bbase + (size_t)(q * 32 + srow) * K + kofs),
                (__attribute__((address_space(3))) void*)(&Bs[q * 2048 + tid * 8]), 16, 0, 0);
    };

    const int lr = lane & 15, hk = lane >> 4;
    const int px0 = (hk ^ (lr & 7)) * 8;             // kstep0 physical chunk (elems)
    const int px1 = px0 ^ 32;                        // kstep1
    const int arow = (wm * 64 + lr) * 64;
    const int brow = (wn * 64 + lr) * 64;

    f32x4 acc[4][4] = {};
    const int nkt = K >> 6;

    for (int t = 0; t < nkt; ++t) {
        stage(t);
        __syncthreads();                 // drains vmcnt(0): stage(t) landed

        const unsigned short* Ab = &As[arow];
        const unsigned short* Bb = &Bs[brow];

        bf16x8 a0[4], b0[4], a1[4], b1[4];
        #pragma unroll
        for (int i = 0; i < 4; ++i) { b0[i] = *(const bf16x8*)(Bb + i * 1024 + px0);
                                      a0[i] = *(const bf16x8*)(Ab + i * 1024 + px0); }
        #pragma unroll
        for (int i = 0; i < 4; ++i) { b1[i] = *(const bf16x8*)(Bb + i * 1024 + px1);
                                      a1[i] = *(const bf16x8*)(Ab + i * 1024 + px1); }
        __builtin_amdgcn_s_setprio(1);
        #pragma unroll
        for (int mi = 0; mi < 4; ++mi)
            #pragma unroll
            for (int ni = 0; ni < 4; ++ni)
                acc[mi][ni] = __builtin_amdgcn_mfma_f32_16x16x32_bf16(a0[mi], b0[ni], acc[mi][ni], 0, 0, 0);
        __builtin_amdgcn_s_setprio(0);
        __builtin_amdgcn_s_setprio(1);
        #pragma unroll
        for (int mi = 0; mi < 4; ++mi)
            #pragma unroll
            for (int ni = 0; ni < 4; ++ni)
                acc[mi][ni] = __builtin_amdgcn_mfma_f32_16x16x32_bf16(a1[mi], b1[ni], acc[mi][ni], 0, 0, 0);
        __builtin_amdgcn_s_setprio(0);
        __syncthreads();                 // all reads done before next overwrite
    }

    #pragma unroll
    for (int mi = 0; mi < 4; ++mi) {
        #pragma unroll
        for (int ni = 0; ni < 4; ++ni) {
            const int gcol = bn * 128 + wn * 64 + ni * 16 + lr;
            #pragma unroll
            for (int r = 0; r < 4; ++r) {
                const int grow = bm * 128 + wm * 64 + mi * 16 + hk * 4 + r;
                if (MODE == 0) {
                    const int which = gcol >> 10;              // 0=Q 1=K 2=V
                    const int col = gcol & 1023;
                    const float* bp = (which == 0) ? bias0 : (which == 1) ? bias1 : bias2;
                    const float v = acc[mi][ni][r] + bp[col];
                    const int b_ = grow >> 10, s_ = grow & 1023, h_ = col >> 6, d_ = col & 63;
                    outH[(size_t)which * (ROWS * 1024) +
                         (size_t)(b_ * NHEADS + h_) * 65536 + s_ * 64 + d_] = f2bf(v);
                } else if (MODE == 2) {
                    const float v = acc[mi][ni][r] + bias0[gcol];
                    const size_t idx = (size_t)grow * N + gcol;
                    outF[idx] = resid[idx] + v;
                }
            }
        }
    }
}

// ---------------- 8-phase 256x256 GEMM (m201 template port), gelu epilogue ----
// 512 threads = 8 waves (2M x 4N), per-wave 128x64. BK=64. LDS 128 KB dbuf,
// A/B each split into 2 halves of 128 rows. Per K-tile: 4 phases, each
// {stage 1 half of tile t+1 | [P0: counted vmcnt(2)] | s_barrier | ds-reads
//  (compiler lgkmcnt) | setprio + 16 MFMA | s_barrier}. vmcnt never drains to
// 0 mid-loop (T4). Swizzle: chunk c at physical c^(row&7), source pre-swizzled
// (rule #21); gload_lds dest = wave-uniform base + lane*16B (slot = j*512+tid).
__global__ __launch_bounds__(512) void gemm8p(
    const unsigned short* __restrict__ A, const unsigned short* __restrict__ Bt,
    const float* __restrict__ bias, unsigned short* __restrict__ outH,
    int N, int K, int gn)
{
    __shared__ __align__(16) unsigned short As[2][16384];  // [buf][half][128x64]
    __shared__ __align__(16) unsigned short Bs[2][16384];

    const int tid = threadIdx.x, lane = tid & 63;
    const int w = tid >> 6;
    const int wm = w >> 2, wn = w & 3;            // 2M x 4N

    const int nwg = gridDim.x;
    const int swzb = (blockIdx.x & 7) * (nwg >> 3) + (blockIdx.x >> 3);
    const int bm = swzb / gn, bn = swzb % gn;

    const int srow = tid >> 3;                    // 0..63 (row within j-group)
    const int sc   = tid & 7;                     // logical chunk
    const unsigned short* Abase = A  + (size_t)(bm * 256) * K;
    const unsigned short* Bbase = Bt + (size_t)(bn * 256) * K;

    // stage half q (0:A-half0 1:A-half1 2:B-half0 3:B-half1) of K-tile kt
    auto stageHalf = [&](int buf, int kt, int q) {
        const unsigned short* gb = (q >= 2) ? Bbase : Abase;
        unsigned short* lb = ((q >= 2) ? &Bs[buf][0] : &As[buf][0]) + (q & 1) * 8192;
        #pragma unroll
        for (int j = 0; j < 2; ++j) {
            const int row = srow + j * 64;        // 0..127 within half
            __builtin_amdgcn_global_load_lds(
                (__attribute__((address_space(1))) void*)(gb
                    + (size_t)((q & 1) * 128 + row) * K + (size_t)kt * 64
                    + ((sc ^ (row & 7)) * 8)),
                (__attribute__((address_space(3))) void*)(lb + j * 4096 + tid * 8), 16, 0, 0);
        }
    };

    const int lr = lane & 15, hk = lane >> 4;
    const int swz0 = (hk ^ (lr & 7)) * 8;         // kstep0 physical chunk (elems)
    const int swz1 = swz0 ^ 32;                   // kstep1

    f32x4 acc[8][4] = {};
    const int nkt = K >> 6;

    // prologue: all 4 halves of tile 0
    stageHalf(0, 0, 0); stageHalf(0, 0, 1); stageHalf(0, 0, 2); stageHalf(0, 0, 3);

    for (int t = 0; t < nkt; ++t) {
        const int cur = t & 1, nxt = cur ^ 1;
        bf16x8 bfr[4][2];                         // B frags live across phases
        #pragma unroll
        for (int q = 0; q < 4; ++q) {
            if (t + 1 < nkt) stageHalf(nxt, t + 1, q);
            if (q == 0) {
                if (t + 1 < nkt) asm volatile("s_waitcnt vmcnt(2)" ::: "memory");
                else             asm volatile("s_waitcnt vmcnt(0)" ::: "memory");
            }
            __builtin_amdgcn_s_barrier();
            asm volatile("" ::: "memory");
            if (q == 0) {
                const unsigned short* Bb = &Bs[cur][(wn >> 1) * 8192 + (wn & 1) * 4096];
                #pragma unroll
                for (int ni = 0; ni < 4; ++ni) {
                    const unsigned short* p = Bb + (ni * 16 + lr) * 64;
                    bfr[ni][0] = *(const bf16x8*)(p + swz0);
                    bfr[ni][1] = *(const bf16x8*)(p + swz1);
                }
            }
            bf16x8 afr[2][2];
            const unsigned short* Ab = &As[cur][wm * 8192];
            #pragma unroll
            for (int m2 = 0; m2 < 2; ++m2) {
                const unsigned short* p = Ab + ((q * 2 + m2) * 16 + lr) * 64;
                afr[m2][0] = *(const bf16x8*)(p + swz0);
                afr[m2][1] = *(const bf16x8*)(p + swz1);
            }
            __builtin_amdgcn_s_setprio(1);
            #pragma unroll
            for (int ks = 0; ks < 2; ++ks)
                #pragma unroll
                for (int m2 = 0; m2 < 2; ++m2)
                    #pragma unroll
                    for (int ni = 0; ni < 4; ++ni)
                        acc[q * 2 + m2][ni] = __builtin_amdgcn_mfma_f32_16x16x32_bf16(
                            afr[m2][ks], bfr[ni][ks], acc[q * 2 + m2][ni], 0, 0, 0);
            __builtin_amdgcn_s_setprio(0);
            __builtin_amdgcn_s_barrier();
            asm volatile("" ::: "memory");
        }
    }

    #pragma unroll
    for (int mf = 0; mf < 8; ++mf) {
        #pragma unroll
        for (int ni = 0; ni < 4; ++ni) {
            const int gcol = bn * 256 + wn * 64 + ni * 16 + lr;
            #pragma unroll
            for (int r = 0; r < 4; ++r) {
                const int grow = bm * 256 + wm * 128 + mf * 16 + hk * 4 + r;
                const float v = acc[mf][ni][r] + bias[gcol];
                const float t3 = fmaf(0.044715f * v * v, v, v);
                const float e  = __builtin_amdgcn_exp2f(-2.3022086f * t3);
                const float ge = v * __builtin_amdgcn_rcpf(1.0f + e);
                outH[(size_t)grow * N + gcol] = f2bf(ge);
            }
        }
    }
}

// ---------------- flash attention (R6-validated) --------------------------
__global__ __launch_bounds__(256) void attn_kernel(const unsigned short* __restrict__ q,
    const unsigned short* __restrict__ k, const unsigned short* __restrict__ vT,
    unsigned short* __restrict__ out)
{
    __shared__ __align__(16) unsigned short Ks[2][4096];   // [64 kv][64 d], swizzled
    __shared__ __align__(16) unsigned short Vs[2][4096];   // [64 d][64 kv'], swizzled
    const int tid = threadIdx.x, lane = tid & 63, w = tid >> 6;
    const int bh = blockIdx.y;
    const int q0 = blockIdx.x * 64;
    const size_t headBase = (size_t)bh * (SEQ * HD);   // 65536

    const int qrow = q0 + w * 16 + (lane & 15);
    const unsigned short* qp = q + headBase + (size_t)qrow * HD + (lane >> 4) * 8;
    const bf16x8 qf0 = *(const bf16x8*)(qp);
    const bf16x8 qf1 = *(const bf16x8*)(qp + 32);

    float lacc = 0.f;
    f32x4 oacc[4] = {};    // oacc[nd][r] = O^T[d=nd*16+4h+r][q=lane&15]

    const int srow = tid >> 3;                          // 0..31
    const int swz  = ((tid & 7) ^ (srow & 7)) * 8;      // pre-swizzled global chunk
    const int pc   = (lane >> 4) ^ (lane & 7);          // physical chunk for swizzled reads

    auto stage = [&](int buf, int kt) {
        #pragma unroll
        for (int s = 0; s < 2; ++s) {
            const unsigned short* gk = k  + headBase + (size_t)(kt + s * 32 + srow) * HD + swz;
            const unsigned short* gv = vT + headBase + (size_t)(s * 32 + srow) * SEQ + kt + swz;
            __builtin_amdgcn_global_load_lds((__attribute__((address_space(1))) void*)gk,
                (__attribute__((address_space(3))) void*)(&Ks[buf][s * 2048 + w * 512]), 16, 0, 0);
            __builtin_amdgcn_global_load_lds((__attribute__((address_space(1))) void*)gv,
                (__attribute__((address_space(3))) void*)(&Vs[buf][s * 2048 + w * 512]), 16, 0, 0);
        }
    };

    stage(0, 0);
    __syncthreads();

    const float C1 = 0.125f * 1.44269504f;      // fold HD^-0.5 into exp2
    const float C2 = -4.0f * 1.44269504f;       // fixed max M = 4

    for (int t = 0; t < 16; ++t) {
        const int cur = t & 1;
        if (t < 15) stage(cur ^ 1, (t + 1) * 64);

        const unsigned short* KB = &Ks[cur][0];
        const unsigned short* VB = &Vs[cur][0];

        // S^T = K·Q^T: s4[ni][r] = S[q=lane&15][kv = ni*16 + 4h + r]
        f32x4 s4[4] = {};
        #pragma unroll
        for (int ni = 0; ni < 4; ++ni) {
            const unsigned short* pk = KB + (ni * 16 + (lane & 15)) * 64;
            s4[ni] = __builtin_amdgcn_mfma_f32_16x16x32_bf16(*(const bf16x8*)(pk + pc * 8),       qf0, s4[ni], 0, 0, 0);
            s4[ni] = __builtin_amdgcn_mfma_f32_16x16x32_bf16(*(const bf16x8*)(pk + (pc ^ 4) * 8), qf1, s4[ni], 0, 0, 0);
        }

        // fixed-max softmax + in-lane bf16 pack
        unsigned U[4][2];
        float ls = 0.f;
        #pragma unroll
        for (int ni = 0; ni < 4; ++ni) {
            const float p0 = __builtin_amdgcn_exp2f(fmaf(s4[ni][0], C1, C2));
            const float p1 = __builtin_amdgcn_exp2f(fmaf(s4[ni][1], C1, C2));
            const float p2 = __builtin_amdgcn_exp2f(fmaf(s4[ni][2], C1, C2));
            const float p3 = __builtin_amdgcn_exp2f(fmaf(s4[ni][3], C1, C2));
            ls += (p0 + p1) + (p2 + p3);
            asm("v_cvt_pk_bf16_f32 %0, %1, %2" : "=v"(U[ni][0]) : "v"(p0), "v"(p1));
            asm("v_cvt_pk_bf16_f32 %0, %1, %2" : "=v"(U[ni][1]) : "v"(p2), "v"(p3));
        }
        lacc += ls;

        union { unsigned u[4]; bf16x8 v; } W0, W1;
        W0.u[0] = U[0][0]; W0.u[1] = U[0][1]; W0.u[2] = U[1][0]; W0.u[3] = U[1][1];
        W1.u[0] = U[2][0]; W1.u[1] = U[2][1]; W1.u[2] = U[3][0]; W1.u[3] = U[3][1];

        // O^T += V^T · P
        #pragma unroll
        for (int nd = 0; nd < 4; ++nd) {
            const unsigned short* pv = VB + (nd * 16 + (lane & 15)) * 64;
            oacc[nd] = __builtin_amdgcn_mfma_f32_16x16x32_bf16(*(const bf16x8*)(pv + pc * 8),       W0.v, oacc[nd], 0, 0, 0);
            oacc[nd] = __builtin_amdgcn_mfma_f32_16x16x32_bf16(*(const bf16x8*)(pv + (pc ^ 4) * 8), W1.v, oacc[nd], 0, 0, 0);
        }

        __syncthreads();
    }

    float l = lacc;
    l += __shfl_xor(l, 16);
    l += __shfl_xor(l, 32);
    const float inv = 1.0f / l;

    const int b_ = bh >> 4, h_ = bh & 15;
    const int s_ = q0 + w * 16 + (lane & 15);
    const int hh = (lane >> 4) * 4;
    #pragma unroll
    for (int nd = 0; nd < 4; ++nd) {
        ushort4 o;
        o.x = f2bf(oacc[nd][0] * inv);
        o.y = f2bf(oacc[nd][1] * inv);
        o.z = f2bf(oacc[nd][2] * inv);
        o.w = f2bf(oacc[nd][3] * inv);
        *(ushort4*)(out + (size_t)(b_ * SEQ + s_) * H_DIM + h_ * 64 + nd * 16 + hh) = o;
    }
}

extern "C" void kernel_launch(void* const* d_in, const int* in_sizes, int n_in,
                              void* d_out, int out_size, void* d_ws, size_t ws_size,
                              hipStream_t stream)
{
    const float* x    = (const float*)d_in[0];
    const float* ln1g = (const float*)d_in[1];
    const float* ln1b = (const float*)d_in[2];
    const float* Wq   = (const float*)d_in[3];
    const float* bq   = (const float*)d_in[4];
    const float* Wk   = (const float*)d_in[5];
    const float* bk   = (const float*)d_in[6];
    const float* Wv   = (const float*)d_in[7];
    const float* bv   = (const float*)d_in[8];
    const float* Wo   = (const float*)d_in[9];
    const float* bo   = (const float*)d_in[10];
    const float* ln2g = (const float*)d_in[11];
    const float* ln2b = (const float*)d_in[12];
    const float* W1   = (const float*)d_in[13];
    const float* b1   = (const float*)d_in[14];
    const float* W2   = (const float*)d_in[15];
    const float* b2   = (const float*)d_in[16];
    float* out = (float*)d_out;

    char* ws = (char*)d_ws;
    const size_t MB = 1024 * 1024;
    unsigned short* h1  = (unsigned short*)(ws);
    unsigned short* qb  = (unsigned short*)(ws + 16 * MB);
    unsigned short* kb  = (unsigned short*)(ws + 32 * MB);
    unsigned short* vb  = (unsigned short*)(ws + 48 * MB);
    unsigned short* vTb = (unsigned short*)(ws + 64 * MB);
    unsigned short* mlp = (unsigned short*)(ws + 16 * MB);
    unsigned short* ao  = h1;
    unsigned short* WqT = (unsigned short*)(ws + 80 * MB);   // contiguous QKV weights
    unsigned short* WkT = (unsigned short*)(ws + 82 * MB);
    unsigned short* WvT = (unsigned short*)(ws + 84 * MB);
    unsigned short* WoT = (unsigned short*)(ws + 86 * MB);
    unsigned short* W1T = (unsigned short*)(ws + 88 * MB);   // 8MB
    unsigned short* W2T = (unsigned short*)(ws + 96 * MB);   // 8MB

    const dim3 tb(32, 8);
    transpose_w<<<dim3(32, 32),  tb, 0, stream>>>(Wq, WqT, 1024, 1024);
    transpose_w<<<dim3(32, 32),  tb, 0, stream>>>(Wk, WkT, 1024, 1024);
    transpose_w<<<dim3(32, 32),  tb, 0, stream>>>(Wv, WvT, 1024, 1024);
    transpose_w<<<dim3(32, 32),  tb, 0, stream>>>(Wo, WoT, 1024, 1024);
    transpose_w<<<dim3(128, 32), tb, 0, stream>>>(W1, W1T, 1024, 4096);
    transpose_w<<<dim3(32, 128), tb, 0, stream>>>(W2, W2T, 4096, 1024);

    ln_kernel<<<ROWS, 256, 0, stream>>>(x, ln1g, ln1b, h1);

    // fused QKV: N = 3072, tile 128x128 -> grid 64x24 = 1536 blocks (R9 config)
    gemm_dp<0><<<1536, 256, 0, stream>>>(h1, WqT, bq, bk, bv, nullptr, nullptr, qb, 3072, 1024, 24);

    transpose_v<<<dim3(2, 32, 128), tb, 0, stream>>>(vb, vTb);

    attn_kernel<<<dim3(16, 128), 256, 0, stream>>>(qb, kb, vTb, ao);

    // O-proj + residual: 64x8 = 512 blocks (R9 config)
    gemm_dp<2><<<512, 256, 0, stream>>>(ao, WoT, bo, bo, bo, x, out, nullptr, 1024, 1024, 8);

    ln_kernel<<<ROWS, 256, 0, stream>>>(out, ln2g, ln2b, h1);

    // MLP1 + gelu: 8-phase 256x256 -> 32x16 = 512 blocks (2 exact rounds)
    gemm8p<<<512, 512, 0, stream>>>(h1, W1T, b1, mlp, 4096, 1024, 16);
    // MLP2 + residual: 64x8 = 512 blocks (R9 config)
    gemm_dp<2><<<512, 256, 0, stream>>>(mlp, W2T, b2, b2, b2, out, out, nullptr, 1024, 4096, 8);
}

// Round 12
// 379.038 us; speedup vs baseline: 1.1488x; 1.0443x over previous
//
#include <hip/hip_runtime.h>

#define H_DIM 1024
#define NHEADS 16
#define HD 64
#define SEQ 1024
#define BATCH 8
#define ROWS (BATCH*SEQ)   // 8192
#define MLPD 4096

typedef __bf16 bf16x8 __attribute__((ext_vector_type(8)));
typedef float f32x4 __attribute__((ext_vector_type(4)));

__device__ __forceinline__ unsigned short f2bf(float f) {
    unsigned u = __float_as_uint(f);
    unsigned r = u + 0x7FFFu + ((u >> 16) & 1u);   // RNE
    return (unsigned short)(r >> 16);
}

// ---------------- weight transpose fp32(K,N) -> bf16(N,K) ----------------
__global__ void transpose_w(const float* __restrict__ in, unsigned short* __restrict__ out,
                            int K, int N)
{
    __shared__ float tile[32][33];
    const int n0 = blockIdx.x * 32, k0 = blockIdx.y * 32;
    const int tx = threadIdx.x, ty = threadIdx.y;      // (32,8)
    #pragma unroll
    for (int i = ty; i < 32; i += 8)
        tile[i][tx] = in[(size_t)(k0 + i) * N + n0 + tx];
    __syncthreads();
    #pragma unroll
    for (int i = ty; i < 32; i += 8)
        out[(size_t)(n0 + i) * K + k0 + tx] = f2bf(tile[tx][i]);
}

// ---- per-head bf16 transpose with kv-permuted columns (R6-validated) ----
__global__ void transpose_v(const unsigned short* __restrict__ in,
                            unsigned short* __restrict__ out)
{
    __shared__ unsigned short tile[32][33];
    const size_t base = (size_t)blockIdx.z * (SEQ * HD);
    const int d0 = blockIdx.x * 32, s0 = blockIdx.y * 32;
    const int tx = threadIdx.x, ty = threadIdx.y;      // (32,8)
    #pragma unroll
    for (int i = ty; i < 32; i += 8)
        tile[i][tx] = in[base + (size_t)(s0 + i) * HD + d0 + tx];
    __syncthreads();
    const int fx = ((tx & 12) << 1) | ((tx & 16) >> 2) | (tx & 3);   // kv -> kv'
    #pragma unroll
    for (int i = ty; i < 32; i += 8)
        out[base + (size_t)(d0 + i) * SEQ + s0 + fx] = tile[tx][i];
}

// ---------------- layernorm fp32 -> bf16, one block per row ----------------
__global__ __launch_bounds__(256) void ln_kernel(const float* __restrict__ x,
    const float* __restrict__ g, const float* __restrict__ b,
    unsigned short* __restrict__ out)
{
    __shared__ float red[4];
    const int row = blockIdx.x;
    const int tid = threadIdx.x;
    const float4 v = *(const float4*)(x + (size_t)row * H_DIM + tid * 4);
    float s = v.x + v.y + v.z + v.w;
    #pragma unroll
    for (int off = 32; off >= 1; off >>= 1) s += __shfl_xor(s, off);
    if ((tid & 63) == 0) red[tid >> 6] = s;
    __syncthreads();
    const float mu = (red[0] + red[1] + red[2] + red[3]) * (1.0f / H_DIM);
    __syncthreads();
    const float dx = v.x - mu, dy = v.y - mu, dz = v.z - mu, dw = v.w - mu;
    float q = dx * dx + dy * dy + dz * dz + dw * dw;
    #pragma unroll
    for (int off = 32; off >= 1; off >>= 1) q += __shfl_xor(q, off);
    if ((tid & 63) == 0) red[tid >> 6] = q;
    __syncthreads();
    const float var = (red[0] + red[1] + red[2] + red[3]) * (1.0f / H_DIM);
    const float rstd = rsqrtf(var + 1e-6f);
    const float4 gv = *(const float4*)(g + tid * 4);
    const float4 bv = *(const float4*)(b + tid * 4);
    ushort4 o;
    o.x = f2bf(dx * rstd * gv.x + bv.x);
    o.y = f2bf(dy * rstd * gv.y + bv.y);
    o.z = f2bf(dz * rstd * gv.z + bv.z);
    o.w = f2bf(dw * rstd * gv.w + bv.w);
    *(ushort4*)(out + (size_t)row * H_DIM + tid * 4) = o;
}

// ---------------- bf16 GEMM (R9-proven): 128x128, 4 waves, single-buffer ----
// MODE 0: fused QKV -> bf16 [B,NH,S,HD] x3    MODE 2: f32 out = resid + C
// MODE 3: bf16 out = gelu_tanh(C)
template<int MODE>
__global__ __launch_bounds__(256) void gemm_dp(
    const unsigned short* __restrict__ A, const unsigned short* __restrict__ Bt,
    const float* __restrict__ bias0, const float* __restrict__ bias1,
    const float* __restrict__ bias2, const float* resid,
    float* outF, unsigned short* __restrict__ outH,
    int N, int K, int gn)
{
    __shared__ __align__(16) unsigned short As[128 * 64];   // 16 KB
    __shared__ __align__(16) unsigned short Bs[128 * 64];   // 16 KB

    const int tid = threadIdx.x, lane = tid & 63;
    const int w = tid >> 6;
    const int wm = w >> 1, wn = w & 1;  // 2x2 wave grid, 64x64 per wave

    const int nwg = gridDim.x;
    const int swzb = (blockIdx.x & 7) * (nwg >> 3) + (blockIdx.x >> 3);
    const int bm = swzb / gn, bn = swzb % gn;

    const int srow = tid >> 3;                       // 0..31
    const int sc = (tid & 7) ^ (srow & 7);           // pre-swizzled global 16B chunk
    const unsigned short* Abase = A  + (size_t)(bm * 128) * K;
    const unsigned short* Bbase = Bt + (size_t)(bn * 128) * K;

    auto stage = [&](int kt) {
        const size_t kofs = (size_t)kt * 64 + sc * 8;
        #pragma unroll
        for (int q = 0; q < 4; ++q)
            __builtin_amdgcn_global_load_lds(
                (__attribute__((address_space(1))) void*)(Abase + (size_t)(q * 32 + srow) * K + kofs),
                (__attribute__((address_space(3))) void*)(&As[q * 2048 + tid * 8]), 16, 0, 0);
        #pragma unroll
        for (int q = 0; q < 4; ++q)
            __builtin_amdgcn_global_load_lds(
                (__attribute__((address_space(1))) void*)(Bbase + (size_t)(q * 32 + srow) * K + kofs),
                (__attribute__((address_space(3))) void*)(&Bs[q * 2048 + tid * 8]), 16, 0, 0);
    };

    const int lr = lane & 15, hk = lane >> 4;
    const int px0 = (hk ^ (lr & 7)) * 8;             // kstep0 physical chunk (elems)
    const int px1 = px0 ^ 32;                        // kstep1
    const int arow = (wm * 64 + lr) * 64;
    const int brow = (wn * 64 + lr) * 64;

    f32x4 acc[4][4] = {};
    const int nkt = K >> 6;

    for (int t = 0; t < nkt; ++t) {
        stage(t);
        __syncthreads();                 // drains vmcnt(0): stage(t) landed

        const unsigned short* Ab = &As[arow];
        const unsigned short* Bb = &Bs[brow];

        bf16x8 a0[4], b0[4], a1[4], b1[4];
        #pragma unroll
        for (int i = 0; i < 4; ++i) { b0[i] = *(const bf16x8*)(Bb + i * 1024 + px0);
                                      a0[i] = *(const bf16x8*)(Ab + i * 1024 + px0); }
        #pragma unroll
        for (int i = 0; i < 4; ++i) { b1[i] = *(const bf16x8*)(Bb + i * 1024 + px1);
                                      a1[i] = *(const bf16x8*)(Ab + i * 1024 + px1); }
        __builtin_amdgcn_s_setprio(1);
        #pragma unroll
        for (int mi = 0; mi < 4; ++mi)
            #pragma unroll
            for (int ni = 0; ni < 4; ++ni)
                acc[mi][ni] = __builtin_amdgcn_mfma_f32_16x16x32_bf16(a0[mi], b0[ni], acc[mi][ni], 0, 0, 0);
        __builtin_amdgcn_s_setprio(0);
        __builtin_amdgcn_s_setprio(1);
        #pragma unroll
        for (int mi = 0; mi < 4; ++mi)
            #pragma unroll
            for (int ni = 0; ni < 4; ++ni)
                acc[mi][ni] = __builtin_amdgcn_mfma_f32_16x16x32_bf16(a1[mi], b1[ni], acc[mi][ni], 0, 0, 0);
        __builtin_amdgcn_s_setprio(0);
        __syncthreads();                 // all reads done before next overwrite
    }

    #pragma unroll
    for (int mi = 0; mi < 4; ++mi) {
        #pragma unroll
        for (int ni = 0; ni < 4; ++ni) {
            const int gcol = bn * 128 + wn * 64 + ni * 16 + lr;
            #pragma unroll
            for (int r = 0; r < 4; ++r) {
                const int grow = bm * 128 + wm * 64 + mi * 16 + hk * 4 + r;
                if (MODE == 0) {
                    const int which = gcol >> 10;              // 0=Q 1=K 2=V
                    const int col = gcol & 1023;
                    const float* bp = (which == 0) ? bias0 : (which == 1) ? bias1 : bias2;
                    const float v = acc[mi][ni][r] + bp[col];
                    const int b_ = grow >> 10, s_ = grow & 1023, h_ = col >> 6, d_ = col & 63;
                    outH[(size_t)which * (ROWS * 1024) +
                         (size_t)(b_ * NHEADS + h_) * 65536 + s_ * 64 + d_] = f2bf(v);
                } else if (MODE == 2) {
                    const float v = acc[mi][ni][r] + bias0[gcol];
                    const size_t idx = (size_t)grow * N + gcol;
                    outF[idx] = resid[idx] + v;
                } else {
                    const float v = acc[mi][ni][r] + bias0[gcol];
                    const float t3 = fmaf(0.044715f * v * v, v, v);
                    const float e  = __builtin_amdgcn_exp2f(-2.3022086f * t3);
                    const float ge = v * __builtin_amdgcn_rcpf(1.0f + e);
                    outH[(size_t)grow * N + gcol] = f2bf(ge);
                }
            }
        }
    }
}

// ---------------- K-phased deep-pipeline 256x256 GEMM, gelu epilogue ---------
// 512 threads = 8 waves (2M x 4N), per-wave 128x64. BK=64 split into 2 k-halves.
// LDS: [2 buf][2 khalf][256 rows][32 elems] per operand = 128 KB total.
// Phase (t,s): stage k-half s of tile t+1 (4 gload_lds) -> vmcnt(8) -> barrier
// -> 12 ds_read_b128 -> setprio + 32 MFMA -> barrier. Data for (t,s) staged at
// (t-1,s): 2 full phases of latency cover; vmcnt(8) keeps 2 newer halves in
// flight (never drains to 0 mid-loop). Swizzle within 32-elem rows:
// phys = c ^ ((row>>1)&3)  -> 8 bank-bases per 16-lane group = conflict-free.
__global__ __launch_bounds__(512) void gemm8k(
    const unsigned short* __restrict__ A, const unsigned short* __restrict__ Bt,
    const float* __restrict__ bias, unsigned short* __restrict__ outH,
    int N, int K, int gn)
{
    __shared__ __align__(16) unsigned short As[2][2][8192];   // 64 KB
    __shared__ __align__(16) unsigned short Bs[2][2][8192];   // 64 KB

    const int tid = threadIdx.x, lane = tid & 63;
    const int w = tid >> 6;
    const int wm = w >> 2, wn = w & 3;            // 2M x 4N; per-wave 128x64

    const int nwg = gridDim.x;
    const int swzb = (blockIdx.x & 7) * (nwg >> 3) + (blockIdx.x >> 3);
    const int bm = swzb / gn, bn = swzb % gn;

    const unsigned short* Abase = A  + (size_t)(bm * 256) * K;
    const unsigned short* Bbase = Bt + (size_t)(bn * 256) * K;

    // staging map (per thread, K-invariant): slot j*512+tid -> (row, phys p)
    int srow[2], soff[2];
    #pragma unroll
    for (int j = 0; j < 2; ++j) {
        const int slot = j * 512 + tid;
        srow[j] = slot >> 2;
        const int p = slot & 3;
        soff[j] = (p ^ ((srow[j] >> 1) & 3)) * 8;   // logical chunk *8 (elems)
    }

    // stage k-half s of tile kt into buf (A+B, 4 loads/thread)
    auto stageKH = [&](int buf, int kt, int s) {
        #pragma unroll
        for (int j = 0; j < 2; ++j) {
            const size_t off = (size_t)srow[j] * K + (size_t)kt * 64 + s * 32 + soff[j];
            __builtin_amdgcn_global_load_lds(
                (__attribute__((address_space(1))) void*)(Abase + off),
                (__attribute__((address_space(3))) void*)(&As[buf][s][(j * 512 + tid) * 8]), 16, 0, 0);
            __builtin_amdgcn_global_load_lds(
                (__attribute__((address_space(1))) void*)(Bbase + off),
                (__attribute__((address_space(3))) void*)(&Bs[buf][s][(j * 512 + tid) * 8]), 16, 0, 0);
        }
    };

    const int lr = lane & 15, hk = lane >> 4;
    // fragment read offsets (elems), K-invariant: row*32 + (hk^((row>>1)&3))*8
    int aoff[8], boff[4];
    #pragma unroll
    for (int mf = 0; mf < 8; ++mf) {
        const int R = wm * 128 + mf * 16 + lr;
        aoff[mf] = R * 32 + ((hk ^ ((R >> 1) & 3)) * 8);
    }
    #pragma unroll
    for (int nf = 0; nf < 4; ++nf) {
        const int R = wn * 64 + nf * 16 + lr;
        boff[nf] = R * 32 + ((hk ^ ((R >> 1) & 3)) * 8);
    }

    f32x4 acc[8][4] = {};
    const int nkt = K >> 6;

    stageKH(0, 0, 0);
    stageKH(0, 0, 1);

    for (int t = 0; t < nkt; ++t) {
        const int buf = t & 1;
        #pragma unroll
        for (int s = 0; s < 2; ++s) {
            if (t + 1 < nkt) {
                stageKH(buf ^ 1, t + 1, s);
                asm volatile("s_waitcnt vmcnt(8)" ::: "memory");   // (t,ks) landed; 2 halves in flight
            } else {
                if (s == 0) asm volatile("s_waitcnt vmcnt(4)" ::: "memory");
                else        asm volatile("s_waitcnt vmcnt(0)" ::: "memory");
            }
            __builtin_amdgcn_s_barrier();
            asm volatile("" ::: "memory");

            const unsigned short* Ar = &As[buf][s][0];
            const unsigned short* Br = &Bs[buf][s][0];
            bf16x8 af[8], bf[4];
            #pragma unroll
            for (int nf = 0; nf < 4; ++nf) bf[nf] = *(const bf16x8*)(Br + boff[nf]);
            #pragma unroll
            for (int mf = 0; mf < 8; ++mf) af[mf] = *(const bf16x8*)(Ar + aoff[mf]);

            __builtin_amdgcn_s_setprio(1);
            #pragma unroll
            for (int mf = 0; mf < 8; ++mf)
                #pragma unroll
                for (int nf = 0; nf < 4; ++nf)
                    acc[mf][nf] = __builtin_amdgcn_mfma_f32_16x16x32_bf16(af[mf], bf[nf], acc[mf][nf], 0, 0, 0);
            __builtin_amdgcn_s_setprio(0);
            __builtin_amdgcn_s_barrier();
            asm volatile("" ::: "memory");
        }
    }

    #pragma unroll
    for (int mf = 0; mf < 8; ++mf) {
        #pragma unroll
        for (int nf = 0; nf < 4; ++nf) {
            const int gcol = bn * 256 + wn * 64 + nf * 16 + lr;
            #pragma unroll
            for (int r = 0; r < 4; ++r) {
                const int grow = bm * 256 + wm * 128 + mf * 16 + hk * 4 + r;
                const float v = acc[mf][nf][r] + bias[gcol];
                const float t3 = fmaf(0.044715f * v * v, v, v);
                const float e  = __builtin_amdgcn_exp2f(-2.3022086f * t3);
                const float ge = v * __builtin_amdgcn_rcpf(1.0f + e);
                outH[(size_t)grow * N + gcol] = f2bf(ge);
            }
        }
    }
}

// ---------------- flash attention (R6-validated) --------------------------
__global__ __launch_bounds__(256) void attn_kernel(const unsigned short* __restrict__ q,
    const unsigned short* __restrict__ k, const unsigned short* __restrict__ vT,
    unsigned short* __restrict__ out)
{
    __shared__ __align__(16) unsigned short Ks[2][4096];   // [64 kv][64 d], swizzled
    __shared__ __align__(16) unsigned short Vs[2][4096];   // [64 d][64 kv'], swizzled
    const int tid = threadIdx.x, lane = tid & 63, w = tid >> 6;
    const int bh = blockIdx.y;
    const int q0 = blockIdx.x * 64;
    const size_t headBase = (size_t)bh * (SEQ * HD);   // 65536

    const int qrow = q0 + w * 16 + (lane & 15);
    const unsigned short* qp = q + headBase + (size_t)qrow * HD + (lane >> 4) * 8;
    const bf16x8 qf0 = *(const bf16x8*)(qp);
    const bf16x8 qf1 = *(const bf16x8*)(qp + 32);

    float lacc = 0.f;
    f32x4 oacc[4] = {};    // oacc[nd][r] = O^T[d=nd*16+4h+r][q=lane&15]

    const int srow = tid >> 3;                          // 0..31
    const int swz  = ((tid & 7) ^ (srow & 7)) * 8;      // pre-swizzled global chunk
    const int pc   = (lane >> 4) ^ (lane & 7);          // physical chunk for swizzled reads

    auto stage = [&](int buf, int kt) {
        #pragma unroll
        for (int s = 0; s < 2; ++s) {
            const unsigned short* gk = k  + headBase + (size_t)(kt + s * 32 + srow) * HD + swz;
            const unsigned short* gv = vT + headBase + (size_t)(s * 32 + srow) * SEQ + kt + swz;
            __builtin_amdgcn_global_load_lds((__attribute__((address_space(1))) void*)gk,
                (__attribute__((address_space(3))) void*)(&Ks[buf][s * 2048 + w * 512]), 16, 0, 0);
            __builtin_amdgcn_global_load_lds((__attribute__((address_space(1))) void*)gv,
                (__attribute__((address_space(3))) void*)(&Vs[buf][s * 2048 + w * 512]), 16, 0, 0);
        }
    };

    stage(0, 0);
    __syncthreads();

    const float C1 = 0.125f * 1.44269504f;      // fold HD^-0.5 into exp2
    const float C2 = -4.0f * 1.44269504f;       // fixed max M = 4

    for (int t = 0; t < 16; ++t) {
        const int cur = t & 1;
        if (t < 15) stage(cur ^ 1, (t + 1) * 64);

        const unsigned short* KB = &Ks[cur][0];
        const unsigned short* VB = &Vs[cur][0];

        // S^T = K·Q^T: s4[ni][r] = S[q=lane&15][kv = ni*16 + 4h + r]
        f32x4 s4[4] = {};
        #pragma unroll
        for (int ni = 0; ni < 4; ++ni) {
            const unsigned short* pk = KB + (ni * 16 + (lane & 15)) * 64;
            s4[ni] = __builtin_amdgcn_mfma_f32_16x16x32_bf16(*(const bf16x8*)(pk + pc * 8),       qf0, s4[ni], 0, 0, 0);
            s4[ni] = __builtin_amdgcn_mfma_f32_16x16x32_bf16(*(const bf16x8*)(pk + (pc ^ 4) * 8), qf1, s4[ni], 0, 0, 0);
        }

        // fixed-max softmax + in-lane bf16 pack
        unsigned U[4][2];
        float ls = 0.f;
        #pragma unroll
        for (int ni = 0; ni < 4; ++ni) {
            const float p0 = __builtin_amdgcn_exp2f(fmaf(s4[ni][0], C1, C2));
            const float p1 = __builtin_amdgcn_exp2f(fmaf(s4[ni][1], C1, C2));
            const float p2 = __builtin_amdgcn_exp2f(fmaf(s4[ni][2], C1, C2));
            const float p3 = __builtin_amdgcn_exp2f(fmaf(s4[ni][3], C1, C2));
            ls += (p0 + p1) + (p2 + p3);
            asm("v_cvt_pk_bf16_f32 %0, %1, %2" : "=v"(U[ni][0]) : "v"(p0), "v"(p1));
            asm("v_cvt_pk_bf16_f32 %0, %1, %2" : "=v"(U[ni][1]) : "v"(p2), "v"(p3));
        }
        lacc += ls;

        union { unsigned u[4]; bf16x8 v; } W0, W1;
        W0.u[0] = U[0][0]; W0.u[1] = U[0][1]; W0.u[2] = U[1][0]; W0.u[3] = U[1][1];
        W1.u[0] = U[2][0]; W1.u[1] = U[2][1]; W1.u[2] = U[3][0]; W1.u[3] = U[3][1];

        // O^T += V^T · P
        #pragma unroll
        for (int nd = 0; nd < 4; ++nd) {
            const unsigned short* pv = VB + (nd * 16 + (lane & 15)) * 64;
            oacc[nd] = __builtin_amdgcn_mfma_f32_16x16x32_bf16(*(const bf16x8*)(pv + pc * 8),       W0.v, oacc[nd], 0, 0, 0);
            oacc[nd] = __builtin_amdgcn_mfma_f32_16x16x32_bf16(*(const bf16x8*)(pv + (pc ^ 4) * 8), W1.v, oacc[nd], 0, 0, 0);
        }

        __syncthreads();
    }

    float l = lacc;
    l += __shfl_xor(l, 16);
    l += __shfl_xor(l, 32);
    const float inv = 1.0f / l;

    const int b_ = bh >> 4, h_ = bh & 15;
    const int s_ = q0 + w * 16 + (lane & 15);
    const int hh = (lane >> 4) * 4;
    #pragma unroll
    for (int nd = 0; nd < 4; ++nd) {
        ushort4 o;
        o.x = f2bf(oacc[nd][0] * inv);
        o.y = f2bf(oacc[nd][1] * inv);
        o.z = f2bf(oacc[nd][2] * inv);
        o.w = f2bf(oacc[nd][3] * inv);
        *(ushort4*)(out + (size_t)(b_ * SEQ + s_) * H_DIM + h_ * 64 + nd * 16 + hh) = o;
    }
}

extern "C" void kernel_launch(void* const* d_in, const int* in_sizes, int n_in,
                              void* d_out, int out_size, void* d_ws, size_t ws_size,
                              hipStream_t stream)
{
    const float* x    = (const float*)d_in[0];
    const float* ln1g = (const float*)d_in[1];
    const float* ln1b = (const float*)d_in[2];
    const float* Wq   = (const float*)d_in[3];
    const float* bq   = (const float*)d_in[4];
    const float* Wk   = (const float*)d_in[5];
    const float* bk   = (const float*)d_in[6];
    const float* Wv   = (const float*)d_in[7];
    const float* bv   = (const float*)d_in[8];
    const float* Wo   = (const float*)d_in[9];
    const float* bo   = (const float*)d_in[10];
    const float* ln2g = (const float*)d_in[11];
    const float* ln2b = (const float*)d_in[12];
    const float* W1   = (const float*)d_in[13];
    const float* b1   = (const float*)d_in[14];
    const float* W2   = (const float*)d_in[15];
    const float* b2   = (const float*)d_in[16];
    float* out = (float*)d_out;

    char* ws = (char*)d_ws;
    const size_t MB = 1024 * 1024;
    unsigned short* h1  = (unsigned short*)(ws);
    unsigned short* qb  = (unsigned short*)(ws + 16 * MB);
    unsigned short* kb  = (unsigned short*)(ws + 32 * MB);
    unsigned short* vb  = (unsigned short*)(ws + 48 * MB);
    unsigned short* vTb = (unsigned short*)(ws + 64 * MB);
    unsigned short* mlp = (unsigned short*)(ws + 16 * MB);
    unsigned short* ao  = h1;
    unsigned short* WqT = (unsigned short*)(ws + 80 * MB);   // contiguous QKV weights
    unsigned short* WkT = (unsigned short*)(ws + 82 * MB);
    unsigned short* WvT = (unsigned short*)(ws + 84 * MB);
    unsigned short* WoT = (unsigned short*)(ws + 86 * MB);
    unsigned short* W1T = (unsigned short*)(ws + 88 * MB);   // 8MB
    unsigned short* W2T = (unsigned short*)(ws + 96 * MB);   // 8MB

    const dim3 tb(32, 8);
    transpose_w<<<dim3(32, 32),  tb, 0, stream>>>(Wq, WqT, 1024, 1024);
    transpose_w<<<dim3(32, 32),  tb, 0, stream>>>(Wk, WkT, 1024, 1024);
    transpose_w<<<dim3(32, 32),  tb, 0, stream>>>(Wv, WvT, 1024, 1024);
    transpose_w<<<dim3(32, 32),  tb, 0, stream>>>(Wo, WoT, 1024, 1024);
    transpose_w<<<dim3(128, 32), tb, 0, stream>>>(W1, W1T, 1024, 4096);
    transpose_w<<<dim3(32, 128), tb, 0, stream>>>(W2, W2T, 4096, 1024);

    ln_kernel<<<ROWS, 256, 0, stream>>>(x, ln1g, ln1b, h1);

    // fused QKV: N = 3072, tile 128x128 -> grid 64x24 = 1536 blocks (R9 config)
    gemm_dp<0><<<1536, 256, 0, stream>>>(h1, WqT, bq, bk, bv, nullptr, nullptr, qb, 3072, 1024, 24);

    transpose_v<<<dim3(2, 32, 128), tb, 0, stream>>>(vb, vTb);

    attn_kernel<<<dim3(16, 128), 256, 0, stream>>>(qb, kb, vTb, ao);

    // O-proj + residual: 64x8 = 512 blocks (R9 config)
    gemm_dp<2><<<512, 256, 0, stream>>>(ao, WoT, bo, bo, bo, x, out, nullptr, 1024, 1024, 8);

    ln_kernel<<<ROWS, 256, 0, stream>>>(out, ln2g, ln2b, h1);

    // MLP1 + gelu: K-phased 256x256 -> 32x16 = 512 blocks (2 exact rounds)
    gemm8k<<<512, 512, 0, stream>>>(h1, W1T, b1, mlp, 4096, 1024, 16);
    // MLP2 + residual: 64x8 = 512 blocks (R9 config)
    gemm_dp<2><<<512, 256, 0, stream>>>(mlp, W2T, b2, b2, b2, out, out, nullptr, 1024, 4096, 8);
}

// Round 13
// 362.681 us; speedup vs baseline: 1.2006x; 1.0451x over previous
//
#include <hip/hip_runtime.h>

#define H_DIM 1024
#define NHEADS 16
#define HD 64
#define SEQ 1024
#define BATCH 8
#define ROWS (BATCH*SEQ)   // 8192
#define MLPD 4096

typedef __bf16 bf16x8 __attribute__((ext_vector_type(8)));
typedef float f32x4 __attribute__((ext_vector_type(4)));

__device__ __forceinline__ unsigned short f2bf(float f) {
    unsigned u = __float_as_uint(f);
    unsigned r = u + 0x7FFFu + ((u >> 16) & 1u);   // RNE
    return (unsigned short)(r >> 16);
}

// ---------------- weight transpose fp32(K,N) -> bf16(N,K) ----------------
__global__ void transpose_w(const float* __restrict__ in, unsigned short* __restrict__ out,
                            int K, int N)
{
    __shared__ float tile[32][33];
    const int n0 = blockIdx.x * 32, k0 = blockIdx.y * 32;
    const int tx = threadIdx.x, ty = threadIdx.y;      // (32,8)
    #pragma unroll
    for (int i = ty; i < 32; i += 8)
        tile[i][tx] = in[(size_t)(k0 + i) * N + n0 + tx];
    __syncthreads();
    #pragma unroll
    for (int i = ty; i < 32; i += 8)
        out[(size_t)(n0 + i) * K + k0 + tx] = f2bf(tile[tx][i]);
}

// ---- per-head bf16 transpose with kv-permuted columns (R6-validated) ----
__global__ void transpose_v(const unsigned short* __restrict__ in,
                            unsigned short* __restrict__ out)
{
    __shared__ unsigned short tile[32][33];
    const size_t base = (size_t)blockIdx.z * (SEQ * HD);
    const int d0 = blockIdx.x * 32, s0 = blockIdx.y * 32;
    const int tx = threadIdx.x, ty = threadIdx.y;      // (32,8)
    #pragma unroll
    for (int i = ty; i < 32; i += 8)
        tile[i][tx] = in[base + (size_t)(s0 + i) * HD + d0 + tx];
    __syncthreads();
    const int fx = ((tx & 12) << 1) | ((tx & 16) >> 2) | (tx & 3);   // kv -> kv'
    #pragma unroll
    for (int i = ty; i < 32; i += 8)
        out[base + (size_t)(d0 + i) * SEQ + s0 + fx] = tile[tx][i];
}

// ---------------- layernorm fp32 -> bf16, one block per row ----------------
__global__ __launch_bounds__(256) void ln_kernel(const float* __restrict__ x,
    const float* __restrict__ g, const float* __restrict__ b,
    unsigned short* __restrict__ out)
{
    __shared__ float red[4];
    const int row = blockIdx.x;
    const int tid = threadIdx.x;
    const float4 v = *(const float4*)(x + (size_t)row * H_DIM + tid * 4);
    float s = v.x + v.y + v.z + v.w;
    #pragma unroll
    for (int off = 32; off >= 1; off >>= 1) s += __shfl_xor(s, off);
    if ((tid & 63) == 0) red[tid >> 6] = s;
    __syncthreads();
    const float mu = (red[0] + red[1] + red[2] + red[3]) * (1.0f / H_DIM);
    __syncthreads();
    const float dx = v.x - mu, dy = v.y - mu, dz = v.z - mu, dw = v.w - mu;
    float q = dx * dx + dy * dy + dz * dz + dw * dw;
    #pragma unroll
    for (int off = 32; off >= 1; off >>= 1) q += __shfl_xor(q, off);
    if ((tid & 63) == 0) red[tid >> 6] = q;
    __syncthreads();
    const float var = (red[0] + red[1] + red[2] + red[3]) * (1.0f / H_DIM);
    const float rstd = rsqrtf(var + 1e-6f);
    const float4 gv = *(const float4*)(g + tid * 4);
    const float4 bv = *(const float4*)(b + tid * 4);
    ushort4 o;
    o.x = f2bf(dx * rstd * gv.x + bv.x);
    o.y = f2bf(dy * rstd * gv.y + bv.y);
    o.z = f2bf(dz * rstd * gv.z + bv.z);
    o.w = f2bf(dw * rstd * gv.w + bv.w);
    *(ushort4*)(out + (size_t)row * H_DIM + tid * 4) = o;
}

// ---------------- bf16 GEMM (R9-proven): 128x128, 4 waves, single-buffer ----
// MODE 0: fused QKV -> bf16 [B,NH,S,HD] x3    MODE 2: f32 out = resid + C
// MODE 3: bf16 out = gelu_tanh(C)
template<int MODE>
__global__ __launch_bounds__(256) void gemm_dp(
    const unsigned short* __restrict__ A, const unsigned short* __restrict__ Bt,
    const float* __restrict__ bias0, const float* __restrict__ bias1,
    const float* __restrict__ bias2, const float* resid,
    float* outF, unsigned short* __restrict__ outH,
    int N, int K, int gn)
{
    __shared__ __align__(16) unsigned short As[128 * 64];   // 16 KB
    __shared__ __align__(16) unsigned short Bs[128 * 64];   // 16 KB

    const int tid = threadIdx.x, lane = tid & 63;
    const int w = tid >> 6;
    const int wm = w >> 1, wn = w & 1;  // 2x2 wave grid, 64x64 per wave

    const int nwg = gridDim.x;
    const int swzb = (blockIdx.x & 7) * (nwg >> 3) + (blockIdx.x >> 3);
    const int bm = swzb / gn, bn = swzb % gn;

    const int srow = tid >> 3;                       // 0..31
    const int sc = (tid & 7) ^ (srow & 7);           // pre-swizzled global 16B chunk
    const unsigned short* Abase = A  + (size_t)(bm * 128) * K;
    const unsigned short* Bbase = Bt + (size_t)(bn * 128) * K;

    auto stage = [&](int kt) {
        const size_t kofs = (size_t)kt * 64 + sc * 8;
        #pragma unroll
        for (int q = 0; q < 4; ++q)
            __builtin_amdgcn_global_load_lds(
                (__attribute__((address_space(1))) void*)(Abase + (size_t)(q * 32 + srow) * K + kofs),
                (__attribute__((address_space(3))) void*)(&As[q * 2048 + tid * 8]), 16, 0, 0);
        #pragma unroll
        for (int q = 0; q < 4; ++q)
            __builtin_amdgcn_global_load_lds(
                (__attribute__((address_space(1))) void*)(Bbase + (size_t)(q * 32 + srow) * K + kofs),
                (__attribute__((address_space(3))) void*)(&Bs[q * 2048 + tid * 8]), 16, 0, 0);
    };

    const int lr = lane & 15, hk = lane >> 4;
    const int px0 = (hk ^ (lr & 7)) * 8;             // kstep0 physical chunk (elems)
    const int px1 = px0 ^ 32;                        // kstep1
    const int arow = (wm * 64 + lr) * 64;
    const int brow = (wn * 64 + lr) * 64;

    f32x4 acc[4][4] = {};
    const int nkt = K >> 6;

    for (int t = 0; t < nkt; ++t) {
        stage(t);
        __syncthreads();                 // drains vmcnt(0): stage(t) landed

        const unsigned short* Ab = &As[arow];
        const unsigned short* Bb = &Bs[brow];

        bf16x8 a0[4], b0[4], a1[4], b1[4];
        #pragma unroll
        for (int i = 0; i < 4; ++i) { b0[i] = *(const bf16x8*)(Bb + i * 1024 + px0);
                                      a0[i] = *(const bf16x8*)(Ab + i * 1024 + px0); }
        #pragma unroll
        for (int i = 0; i < 4; ++i) { b1[i] = *(const bf16x8*)(Bb + i * 1024 + px1);
                                      a1[i] = *(const bf16x8*)(Ab + i * 1024 + px1); }
        __builtin_amdgcn_s_setprio(1);
        #pragma unroll
        for (int mi = 0; mi < 4; ++mi)
            #pragma unroll
            for (int ni = 0; ni < 4; ++ni)
                acc[mi][ni] = __builtin_amdgcn_mfma_f32_16x16x32_bf16(a0[mi], b0[ni], acc[mi][ni], 0, 0, 0);
        __builtin_amdgcn_s_setprio(0);
        __builtin_amdgcn_s_setprio(1);
        #pragma unroll
        for (int mi = 0; mi < 4; ++mi)
            #pragma unroll
            for (int ni = 0; ni < 4; ++ni)
                acc[mi][ni] = __builtin_amdgcn_mfma_f32_16x16x32_bf16(a1[mi], b1[ni], acc[mi][ni], 0, 0, 0);
        __builtin_amdgcn_s_setprio(0);
        __syncthreads();                 // all reads done before next overwrite
    }

    #pragma unroll
    for (int mi = 0; mi < 4; ++mi) {
        #pragma unroll
        for (int ni = 0; ni < 4; ++ni) {
            const int gcol = bn * 128 + wn * 64 + ni * 16 + lr;
            #pragma unroll
            for (int r = 0; r < 4; ++r) {
                const int grow = bm * 128 + wm * 64 + mi * 16 + hk * 4 + r;
                if (MODE == 0) {
                    const int which = gcol >> 10;              // 0=Q 1=K 2=V
                    const int col = gcol & 1023;
                    const float* bp = (which == 0) ? bias0 : (which == 1) ? bias1 : bias2;
                    const float v = acc[mi][ni][r] + bp[col];
                    const int b_ = grow >> 10, s_ = grow & 1023, h_ = col >> 6, d_ = col & 63;
                    outH[(size_t)which * (ROWS * 1024) +
                         (size_t)(b_ * NHEADS + h_) * 65536 + s_ * 64 + d_] = f2bf(v);
                } else if (MODE == 2) {
                    const float v = acc[mi][ni][r] + bias0[gcol];
                    const size_t idx = (size_t)grow * N + gcol;
                    outF[idx] = resid[idx] + v;
                } else {
                    const float v = acc[mi][ni][r] + bias0[gcol];
                    const float t3 = fmaf(0.044715f * v * v, v, v);
                    const float e  = __builtin_amdgcn_exp2f(-2.3022086f * t3);
                    const float ge = v * __builtin_amdgcn_rcpf(1.0f + e);
                    outH[(size_t)grow * N + gcol] = f2bf(ge);
                }
            }
        }
    }
}

// ---------------- K-phased deep-pipeline 256x256 GEMM, gelu epilogue ---------
// R13 schedule fix vs R12: fragment ds_reads moved to phase TOP (before the
// barrier), ONE barrier per phase, vmcnt(4) counted certification.
// Phase (t,s): {12 ds_read of (t,s) data [certified last phase] -> stage
// k-half s of tile t+1 (4 gload_lds) -> vmcnt(4) [certifies (t,s+1) data;
// only just-issued 4 stay in flight] -> s_barrier [publishes] -> setprio +
// 32 MFMA [compiler lgkmcnt]}. Read latency hides under vmcnt+barrier wait.
// W-A-R: write at ph(t,s) is 2 barriers after the reads of its old data
// (ph(t-1,s), consumed by lgkm-waited MFMA before barrier(t-1,s')). Never
// drains vmcnt to 0 mid-loop (T4).
__global__ __launch_bounds__(512) void gemm8k(
    const unsigned short* __restrict__ A, const unsigned short* __restrict__ Bt,
    const float* __restrict__ bias, unsigned short* __restrict__ outH,
    int N, int K, int gn)
{
    __shared__ __align__(16) unsigned short As[2][2][8192];   // 64 KB
    __shared__ __align__(16) unsigned short Bs[2][2][8192];   // 64 KB

    const int tid = threadIdx.x, lane = tid & 63;
    const int w = tid >> 6;
    const int wm = w >> 2, wn = w & 3;            // 2M x 4N; per-wave 128x64

    const int nwg = gridDim.x;
    const int swzb = (blockIdx.x & 7) * (nwg >> 3) + (blockIdx.x >> 3);
    const int bm = swzb / gn, bn = swzb % gn;

    const unsigned short* Abase = A  + (size_t)(bm * 256) * K;
    const unsigned short* Bbase = Bt + (size_t)(bn * 256) * K;

    // staging map (per thread, K-invariant): slot j*512+tid -> (row, phys p)
    int srow[2], soff[2];
    #pragma unroll
    for (int j = 0; j < 2; ++j) {
        const int slot = j * 512 + tid;
        srow[j] = slot >> 2;
        const int p = slot & 3;
        soff[j] = (p ^ ((srow[j] >> 1) & 3)) * 8;   // logical chunk *8 (elems)
    }

    // stage k-half s of tile kt into buf (A+B, 4 loads/thread)
    auto stageKH = [&](int buf, int kt, int s) {
        #pragma unroll
        for (int j = 0; j < 2; ++j) {
            const size_t off = (size_t)srow[j] * K + (size_t)kt * 64 + s * 32 + soff[j];
            __builtin_amdgcn_global_load_lds(
                (__attribute__((address_space(1))) void*)(Abase + off),
                (__attribute__((address_space(3))) void*)(&As[buf][s][(j * 512 + tid) * 8]), 16, 0, 0);
            __builtin_amdgcn_global_load_lds(
                (__attribute__((address_space(1))) void*)(Bbase + off),
                (__attribute__((address_space(3))) void*)(&Bs[buf][s][(j * 512 + tid) * 8]), 16, 0, 0);
        }
    };

    const int lr = lane & 15, hk = lane >> 4;
    // fragment read offsets (elems), K-invariant: row*32 + (hk^((row>>1)&3))*8
    int aoff[8], boff[4];
    #pragma unroll
    for (int mf = 0; mf < 8; ++mf) {
        const int R = wm * 128 + mf * 16 + lr;
        aoff[mf] = R * 32 + ((hk ^ ((R >> 1) & 3)) * 8);
    }
    #pragma unroll
    for (int nf = 0; nf < 4; ++nf) {
        const int R = wn * 64 + nf * 16 + lr;
        boff[nf] = R * 32 + ((hk ^ ((R >> 1) & 3)) * 8);
    }

    f32x4 acc[8][4] = {};
    const int nkt = K >> 6;

    // prologue: both k-halves of tile 0; certify half 0; publish
    stageKH(0, 0, 0);
    stageKH(0, 0, 1);
    asm volatile("s_waitcnt vmcnt(4)" ::: "memory");
    __builtin_amdgcn_s_barrier();
    asm volatile("" ::: "memory");

    for (int t = 0; t < nkt; ++t) {
        const int buf = t & 1;
        #pragma unroll
        for (int s = 0; s < 2; ++s) {
            // 1. fragment reads for (t,s) — certified by previous phase
            const unsigned short* Ar = &As[buf][s][0];
            const unsigned short* Br = &Bs[buf][s][0];
            bf16x8 af[8], bf[4];
            #pragma unroll
            for (int nf = 0; nf < 4; ++nf) bf[nf] = *(const bf16x8*)(Br + boff[nf]);
            #pragma unroll
            for (int mf = 0; mf < 8; ++mf) af[mf] = *(const bf16x8*)(Ar + aoff[mf]);

            // 2. stage k-half s of tile t+1; certify (t,s+1)'s data
            if (t + 1 < nkt) {
                stageKH(buf ^ 1, t + 1, s);
                asm volatile("s_waitcnt vmcnt(4)" ::: "memory");
            } else {
                asm volatile("s_waitcnt vmcnt(0)" ::: "memory");
            }
            // 3. single barrier: publish certification + R/W ordering
            __builtin_amdgcn_s_barrier();
            asm volatile("" ::: "memory");

            // 4. MFMA (compiler inserts lgkmcnt waits on af/bf)
            __builtin_amdgcn_s_setprio(1);
            #pragma unroll
            for (int mf = 0; mf < 8; ++mf)
                #pragma unroll
                for (int nf = 0; nf < 4; ++nf)
                    acc[mf][nf] = __builtin_amdgcn_mfma_f32_16x16x32_bf16(af[mf], bf[nf], acc[mf][nf], 0, 0, 0);
            __builtin_amdgcn_s_setprio(0);
        }
    }

    #pragma unroll
    for (int mf = 0; mf < 8; ++mf) {
        #pragma unroll
        for (int nf = 0; nf < 4; ++nf) {
            const int gcol = bn * 256 + wn * 64 + nf * 16 + lr;
            #pragma unroll
            for (int r = 0; r < 4; ++r) {
                const int grow = bm * 256 + wm * 128 + mf * 16 + hk * 4 + r;
                const float v = acc[mf][nf][r] + bias[gcol];
                const float t3 = fmaf(0.044715f * v * v, v, v);
                const float e  = __builtin_amdgcn_exp2f(-2.3022086f * t3);
                const float ge = v * __builtin_amdgcn_rcpf(1.0f + e);
                outH[(size_t)grow * N + gcol] = f2bf(ge);
            }
        }
    }
}

// ---------------- flash attention (R6-validated) --------------------------
__global__ __launch_bounds__(256) void attn_kernel(const unsigned short* __restrict__ q,
    const unsigned short* __restrict__ k, const unsigned short* __restrict__ vT,
    unsigned short* __restrict__ out)
{
    __shared__ __align__(16) unsigned short Ks[2][4096];   // [64 kv][64 d], swizzled
    __shared__ __align__(16) unsigned short Vs[2][4096];   // [64 d][64 kv'], swizzled
    const int tid = threadIdx.x, lane = tid & 63, w = tid >> 6;
    const int bh = blockIdx.y;
    const int q0 = blockIdx.x * 64;
    const size_t headBase = (size_t)bh * (SEQ * HD);   // 65536

    const int qrow = q0 + w * 16 + (lane & 15);
    const unsigned short* qp = q + headBase + (size_t)qrow * HD + (lane >> 4) * 8;
    const bf16x8 qf0 = *(const bf16x8*)(qp);
    const bf16x8 qf1 = *(const bf16x8*)(qp + 32);

    float lacc = 0.f;
    f32x4 oacc[4] = {};    // oacc[nd][r] = O^T[d=nd*16+4h+r][q=lane&15]

    const int srow = tid >> 3;                          // 0..31
    const int swz  = ((tid & 7) ^ (srow & 7)) * 8;      // pre-swizzled global chunk
    const int pc   = (lane >> 4) ^ (lane & 7);          // physical chunk for swizzled reads

    auto stage = [&](int buf, int kt) {
        #pragma unroll
        for (int s = 0; s < 2; ++s) {
            const unsigned short* gk = k  + headBase + (size_t)(kt + s * 32 + srow) * HD + swz;
            const unsigned short* gv = vT + headBase + (size_t)(s * 32 + srow) * SEQ + kt + swz;
            __builtin_amdgcn_global_load_lds((__attribute__((address_space(1))) void*)gk,
                (__attribute__((address_space(3))) void*)(&Ks[buf][s * 2048 + w * 512]), 16, 0, 0);
            __builtin_amdgcn_global_load_lds((__attribute__((address_space(1))) void*)gv,
                (__attribute__((address_space(3))) void*)(&Vs[buf][s * 2048 + w * 512]), 16, 0, 0);
        }
    };

    stage(0, 0);
    __syncthreads();

    const float C1 = 0.125f * 1.44269504f;      // fold HD^-0.5 into exp2
    const float C2 = -4.0f * 1.44269504f;       // fixed max M = 4

    for (int t = 0; t < 16; ++t) {
        const int cur = t & 1;
        if (t < 15) stage(cur ^ 1, (t + 1) * 64);

        const unsigned short* KB = &Ks[cur][0];
        const unsigned short* VB = &Vs[cur][0];

        // S^T = K·Q^T: s4[ni][r] = S[q=lane&15][kv = ni*16 + 4h + r]
        f32x4 s4[4] = {};
        #pragma unroll
        for (int ni = 0; ni < 4; ++ni) {
            const unsigned short* pk = KB + (ni * 16 + (lane & 15)) * 64;
            s4[ni] = __builtin_amdgcn_mfma_f32_16x16x32_bf16(*(const bf16x8*)(pk + pc * 8),       qf0, s4[ni], 0, 0, 0);
            s4[ni] = __builtin_amdgcn_mfma_f32_16x16x32_bf16(*(const bf16x8*)(pk + (pc ^ 4) * 8), qf1, s4[ni], 0, 0, 0);
        }

        // fixed-max softmax + in-lane bf16 pack
        unsigned U[4][2];
        float ls = 0.f;
        #pragma unroll
        for (int ni = 0; ni < 4; ++ni) {
            const float p0 = __builtin_amdgcn_exp2f(fmaf(s4[ni][0], C1, C2));
            const float p1 = __builtin_amdgcn_exp2f(fmaf(s4[ni][1], C1, C2));
            const float p2 = __builtin_amdgcn_exp2f(fmaf(s4[ni][2], C1, C2));
            const float p3 = __builtin_amdgcn_exp2f(fmaf(s4[ni][3], C1, C2));
            ls += (p0 + p1) + (p2 + p3);
            asm("v_cvt_pk_bf16_f32 %0, %1, %2" : "=v"(U[ni][0]) : "v"(p0), "v"(p1));
            asm("v_cvt_pk_bf16_f32 %0, %1, %2" : "=v"(U[ni][1]) : "v"(p2), "v"(p3));
        }
        lacc += ls;

        union { unsigned u[4]; bf16x8 v; } W0, W1;
        W0.u[0] = U[0][0]; W0.u[1] = U[0][1]; W0.u[2] = U[1][0]; W0.u[3] = U[1][1];
        W1.u[0] = U[2][0]; W1.u[1] = U[2][1]; W1.u[2] = U[3][0]; W1.u[3] = U[3][1];

        // O^T += V^T · P
        #pragma unroll
        for (int nd = 0; nd < 4; ++nd) {
            const unsigned short* pv = VB + (nd * 16 + (lane & 15)) * 64;
            oacc[nd] = __builtin_amdgcn_mfma_f32_16x16x32_bf16(*(const bf16x8*)(pv + pc * 8),       W0.v, oacc[nd], 0, 0, 0);
            oacc[nd] = __builtin_amdgcn_mfma_f32_16x16x32_bf16(*(const bf16x8*)(pv + (pc ^ 4) * 8), W1.v, oacc[nd], 0, 0, 0);
        }

        __syncthreads();
    }

    float l = lacc;
    l += __shfl_xor(l, 16);
    l += __shfl_xor(l, 32);
    const float inv = 1.0f / l;

    const int b_ = bh >> 4, h_ = bh & 15;
    const int s_ = q0 + w * 16 + (lane & 15);
    const int hh = (lane >> 4) * 4;
    #pragma unroll
    for (int nd = 0; nd < 4; ++nd) {
        ushort4 o;
        o.x = f2bf(oacc[nd][0] * inv);
        o.y = f2bf(oacc[nd][1] * inv);
        o.z = f2bf(oacc[nd][2] * inv);
        o.w = f2bf(oacc[nd][3] * inv);
        *(ushort4*)(out + (size_t)(b_ * SEQ + s_) * H_DIM + h_ * 64 + nd * 16 + hh) = o;
    }
}

extern "C" void kernel_launch(void* const* d_in, const int* in_sizes, int n_in,
                              void* d_out, int out_size, void* d_ws, size_t ws_size,
                              hipStream_t stream)
{
    const float* x    = (const float*)d_in[0];
    const float* ln1g = (const float*)d_in[1];
    const float* ln1b = (const float*)d_in[2];
    const float* Wq   = (const float*)d_in[3];
    const float* bq   = (const float*)d_in[4];
    const float* Wk   = (const float*)d_in[5];
    const float* bk   = (const float*)d_in[6];
    const float* Wv   = (const float*)d_in[7];
    const float* bv   = (const float*)d_in[8];
    const float* Wo   = (const float*)d_in[9];
    const float* bo   = (const float*)d_in[10];
    const float* ln2g = (const float*)d_in[11];
    const float* ln2b = (const float*)d_in[12];
    const float* W1   = (const float*)d_in[13];
    const float* b1   = (const float*)d_in[14];
    const float* W2   = (const float*)d_in[15];
    const float* b2   = (const float*)d_in[16];
    float* out = (float*)d_out;

    char* ws = (char*)d_ws;
    const size_t MB = 1024 * 1024;
    unsigned short* h1  = (unsigned short*)(ws);
    unsigned short* qb  = (unsigned short*)(ws + 16 * MB);
    unsigned short* kb  = (unsigned short*)(ws + 32 * MB);
    unsigned short* vb  = (unsigned short*)(ws + 48 * MB);
    unsigned short* vTb = (unsigned short*)(ws + 64 * MB);
    unsigned short* mlp = (unsigned short*)(ws + 16 * MB);
    unsigned short* ao  = h1;
    unsigned short* WqT = (unsigned short*)(ws + 80 * MB);   // contiguous QKV weights
    unsigned short* WkT = (unsigned short*)(ws + 82 * MB);
    unsigned short* WvT = (unsigned short*)(ws + 84 * MB);
    unsigned short* WoT = (unsigned short*)(ws + 86 * MB);
    unsigned short* W1T = (unsigned short*)(ws + 88 * MB);   // 8MB
    unsigned short* W2T = (unsigned short*)(ws + 96 * MB);   // 8MB

    const dim3 tb(32, 8);
    transpose_w<<<dim3(32, 32),  tb, 0, stream>>>(Wq, WqT, 1024, 1024);
    transpose_w<<<dim3(32, 32),  tb, 0, stream>>>(Wk, WkT, 1024, 1024);
    transpose_w<<<dim3(32, 32),  tb, 0, stream>>>(Wv, WvT, 1024, 1024);
    transpose_w<<<dim3(32, 32),  tb, 0, stream>>>(Wo, WoT, 1024, 1024);
    transpose_w<<<dim3(128, 32), tb, 0, stream>>>(W1, W1T, 1024, 4096);
    transpose_w<<<dim3(32, 128), tb, 0, stream>>>(W2, W2T, 4096, 1024);

    ln_kernel<<<ROWS, 256, 0, stream>>>(x, ln1g, ln1b, h1);

    // fused QKV: N = 3072, tile 128x128 -> grid 64x24 = 1536 blocks (R9 config)
    gemm_dp<0><<<1536, 256, 0, stream>>>(h1, WqT, bq, bk, bv, nullptr, nullptr, qb, 3072, 1024, 24);

    transpose_v<<<dim3(2, 32, 128), tb, 0, stream>>>(vb, vTb);

    attn_kernel<<<dim3(16, 128), 256, 0, stream>>>(qb, kb, vTb, ao);

    // O-proj + residual: 64x8 = 512 blocks (R9 config)
    gemm_dp<2><<<512, 256, 0, stream>>>(ao, WoT, bo, bo, bo, x, out, nullptr, 1024, 1024, 8);

    ln_kernel<<<ROWS, 256, 0, stream>>>(out, ln2g, ln2b, h1);

    // MLP1 + gelu: K-phased 256x256 -> 32x16 = 512 blocks (2 exact rounds)
    gemm8k<<<512, 512, 0, stream>>>(h1, W1T, b1, mlp, 4096, 1024, 16);
    // MLP2 + residual: 64x8 = 512 blocks (R9 config)
    gemm_dp<2><<<512, 256, 0, stream>>>(mlp, W2T, b2, b2, b2, out, out, nullptr, 1024, 4096, 8);
}